// Round 7
// baseline (433.962 us; speedup 1.0000x reference)
//
#include <hip/hip_runtime.h>

#define T_LEN  2048
#define NCH    4096     // chains (B)
#define CH     32       // chunk length (timesteps per output chunk)
#define NCHUNK (T_LEN / CH)
#define WARM   256      // warm-up steps before each chunk (chunks 0-7: exact from zero)
#define TK     4        // timesteps per LDS tile (4 KB per tile)
#define NBUF   2        // double buffer: 8 KB LDS -> 16 blocks/CU (4 waves/SIMD)
#define WPC    64       // chains per wave (= block size, 1 wave per block)

__device__ __forceinline__ float clampf(float x, float lo, float hi) {
    return fminf(fmaxf(x, lo), hi);
}

struct Params {
    float insc, C, S, sub, crak, rk, kr, lg, ls, invS, eca;
};

__device__ __forceinline__ Params mkparams(
    const float* pINSC, const float* pCOEFF, const float* pSQ, const float* pSMSC,
    const float* pSUB, const float* pCRAK, const float* pRecK, const float* pKr,
    const float* pLG, const float* pLS)
{
    Params pr;
    pr.insc = clampf(pINSC[0] * 5.f,   0.5f,   5.f);
    pr.C    = clampf(pCOEFF[0] * 400.f, 50.f,  400.f);
    float q = clampf(pSQ[0] * 6.f,     0.f,    6.f);
    pr.S    = clampf(pSMSC[0] * 500.f, 50.f,   500.f);
    pr.sub  = clampf(pSUB[0],          0.f,    1.f);
    pr.crak = clampf(pCRAK[0],         0.f,    1.f);
    pr.rk   = clampf(pRecK[0] * 0.3f,  0.003f, 0.3f);
    pr.kr   = clampf(pKr[0] * 0.1f,    0.01f,  0.1f);
    pr.lg   = clampf(pLG[0] * 0.1f,    0.001f, 0.1f);
    pr.ls   = clampf(pLS[0] * 10.f,    0.01f,  10.f);
    pr.invS = 1.0f / pr.S;
    pr.eca  = -q * pr.invS;
    return pr;
}

// HBM -> LDS direct (no VGPR round trip). LDS dest is wave-uniform base;
// HW writes lane i at dst + i*16. Global src address is per-lane.
__device__ __forceinline__ void gload_lds16(const float4* g, float4* l) {
    __builtin_amdgcn_global_load_lds(
        (const __attribute__((address_space(1))) void*)(g),
        (__attribute__((address_space(3))) void*)(l),
        16, 0, 0);
}

// One recurrence step. OUT=true additionally computes the fused post-pass Q.
template <bool OUT>
__device__ __forceinline__ float step_one(const Params& pr, const float4& xv,
                                          float& sms, float& gw, float& rs)
{
    const float p = xv.x, pet = xv.y, rsmax = xv.z, area = xv.w;

    const float INT  = fminf(fminf(pr.insc, pet), p);
    const float INR  = p - INT;
    const float smsc  = fminf(fmaxf(sms, 0.f), pr.S);
    const float ratio = smsc * pr.invS;
    const float infil = pr.C * __expf(pr.eca * smsc);
    const float RMO   = fminf(infil, INR);
    const float IRUN  = INR - RMO;
    const float SRUN  = pr.sub * ratio * RMO;
    const float REC   = pr.crak * ratio * (RMO - SRUN);
    const float SMF   = (RMO - SRUN) - REC;
    const float POT   = pet - INT;              // INT <= pet always -> max(.,0) redundant
    const float ETS   = fminf(POT, 10.f * ratio);
    const float nsms  = smsc + (SMF - ETS);
    const float RECn  = REC + fmaxf(nsms - pr.S, 0.f);
    const float BAS   = pr.rk * fmaxf(gw, 0.f);
    const float ngw   = (gw - pr.lg) + (RECn - BAS);
    const float inflow = (IRUN + SRUN + BAS) * area;
    const float rinv   = __builtin_amdgcn_rcpf(rsmax);
    const float xr     = (rs + inflow) - rsmax;
    const float Qor    = fmaxf(xr, 0.f);
    const float rrt    = rs * rinv;
    const float Qir    = (xr > 0.f) ? (pr.kr * rsmax)
                                    : (pr.kr * rs * (rrt * __builtin_amdgcn_sqrtf(rrt)));
    const float nrs    = rs + ((inflow - Qor) - Qir);

    float q = 0.f;
    if constexpr (OUT) {
        // fused post-pass (valid for t>=1; t==0 fixed by hirnn_t0_kernel)
        const float xq   = (nrs + inflow) - rsmax;
        const float Qor2 = fmaxf(xq, 0.f);
        const float r2   = nrs * rinv;
        const float Qir2 = (xq > 0.f) ? (pr.kr * rsmax)
                                      : (pr.kr * nrs * (r2 * __builtin_amdgcn_sqrtf(r2)));
        const float oma  = 1.f - area;
        const float dra  = (SRUN + IRUN) * oma + Qir2 + Qor2 - pr.ls;
        q = fmaxf(fmaxf(dra, 0.f) + BAS * oma, 0.f);
    }

    sms = nsms; gw = ngw; rs = nrs;
    return q;
}

// ---------------- main chunked scan kernel ----------------
// CH=32: 64 chunks x 64 chain-groups = 4096 one-wave blocks. 8 KB LDS/block ->
// 16 blocks/CU = 4 waves/SIMD (entire grid co-resident in one dispatch round).
// Rationale (R1/R3/R6 model): per-wave step latency ~550+230w cycles is
// compute-intrinsic (in-order wave, exp/sqrt chains), so throughput scales
// with waves/SIMD; w=4 beats w=1/w=2 despite the extra warm-up work.
// __launch_bounds__(64,4) pins 4 waves/EU (caps VGPR at 128).
//
// Per 4-step tile the wave stages [64 chains x 4 steps] HBM->LDS via 4
// global_load_lds (16 contiguous 64B segments each), double-buffered with
// counted s_waitcnt vmcnt(4) (depth-1 prefetch; TLP hides the rest).
//
// Block decode: blk = chunk*64 + cgrp -> the 9 chunk-windows overlapping a
// given input line are spaced 64 apart = same XCD (64 % 8 == 0) and
// co-resident -> L2 absorbs warm-up re-reads (R4 lesson).
//
// Step index XOR-swizzled on the GLOBAL source address (LDS dest is linear):
// slot (chain c, j) holds step j ^ ((c>>1)&3) -> per-step wave ds_read_b128
// spreads 8 lanes per bank-quad in distinct rows.
__global__ __launch_bounds__(64, 4)
void hirnn_chunk_kernel(const float* __restrict__ inp,
                        const float* __restrict__ pINSC, const float* __restrict__ pCOEFF,
                        const float* __restrict__ pSQ,   const float* __restrict__ pSMSC,
                        const float* __restrict__ pSUB,  const float* __restrict__ pCRAK,
                        const float* __restrict__ pRecK, const float* __restrict__ pKr,
                        const float* __restrict__ pLG,   const float* __restrict__ pLS,
                        float* __restrict__ out, float* __restrict__ ws)
{
    __shared__ float4 buf[NBUF][WPC * TK];     // 2 x 4 KB = 8 KB

    const int l     = threadIdx.x;             // lane 0..63
    const int blk   = blockIdx.x;
    const int chunk = blk >> 6;                // 64 chain-groups per chunk
    const int cgrp  = blk & 63;
    const int cbase = cgrp * WPC;
    const int chain = cbase + l;

    const Params pr = mkparams(pINSC, pCOEFF, pSQ, pSMSC, pSUB, pCRAK, pRecK, pKr, pLG, pLS);

    // Staging map, instruction k (k=0..3): lane l covers
    //   chain = cbase + 16k + (l>>2), global step = t0 + ((l&3) ^ ((l>>3)&3))
    // -> every aligned 4-lane group covers one full 64B segment (16 segs/inst).
    const float4* __restrict__ gl =
        reinterpret_cast<const float4*>(inp)
        + (size_t)(cbase + (l >> 2)) * T_LEN + ((l & 3) ^ ((l >> 3) & 3));

    float4* __restrict__ qout = reinterpret_cast<float4*>(out + (size_t)chain * T_LEN);

    const int t_start = chunk * CH;
    const int t_warm  = (t_start >= WARM) ? (t_start - WARM) : 0;
    const int t_end   = t_start + CH;

    float sms = 0.f, gw = 0.f, rs = 0.f;       // warm-start from zero state

    auto issue_tile = [&](float4* dst, int t0) {
#pragma unroll
        for (int k = 0; k < TK; ++k)
            gload_lds16(gl + (size_t)(k * 16) * T_LEN + t0, dst + k * WPC);
    };

    // prologue: stage first tile
    issue_tile(&buf[0][0], t_warm);

    const int rbase = l * TK;                  // own chain's row base (float4 units)
    const int rx    = (l >> 1) & 3;            // read-side XOR

    int p = 0;
    for (int t0 = t_warm; t0 < t_end; t0 += TK, p ^= 1) {
        if (t0 + TK < t_end) {
            issue_tile(&buf[p ^ 1][0], t0 + TK);          // prefetch next tile
            asm volatile("s_waitcnt vmcnt(4)" ::: "memory");   // current tile resident
        } else {
            asm volatile("s_waitcnt vmcnt(0)" ::: "memory");
        }
        __builtin_amdgcn_sched_barrier(0);

        const float4* bp = &buf[p][0];
        float4 x[TK];
#pragma unroll
        for (int s = 0; s < TK; ++s)
            x[s] = bp[rbase + (s ^ rx)];

        if (t0 < t_start) {                    // warm-up: state only
#pragma unroll
            for (int s = 0; s < TK; ++s) step_one<false>(pr, x[s], sms, gw, rs);
        } else {                               // output phase
            float q[TK];
#pragma unroll
            for (int s = 0; s < TK; ++s) q[s] = step_one<true>(pr, x[s], sms, gw, rs);
            float4 w;
            w.x = q[0]; w.y = q[1]; w.z = q[2]; w.w = q[3];
            qout[t0 / 4] = w;
        }
    }

    if (chunk == NCHUNK - 1) {                 // final state for the t==0 fix-up
        ws[chain * 2 + 0] = sms;
        ws[chain * 2 + 1] = gw;
    }
}

// ---------------- t == 0 fix-up kernel ----------------
// Q[b,0] uses SMS1=final sms, GW1=final gw, RS=rs after step 0 (exact: zero start state).
__global__ __launch_bounds__(256)
void hirnn_t0_kernel(const float* __restrict__ inp,
                     const float* __restrict__ pINSC, const float* __restrict__ pCOEFF,
                     const float* __restrict__ pSQ,   const float* __restrict__ pSMSC,
                     const float* __restrict__ pSUB,  const float* __restrict__ pCRAK,
                     const float* __restrict__ pRecK, const float* __restrict__ pKr,
                     const float* __restrict__ pLG,   const float* __restrict__ pLS,
                     const float* __restrict__ ws, float* __restrict__ out)
{
    const int b = blockIdx.x * blockDim.x + threadIdx.x;
    if (b >= NCH) return;

    const Params pr = mkparams(pINSC, pCOEFF, pSQ, pSMSC, pSUB, pCRAK, pRecK, pKr, pLG, pLS);

    const float4 x0 = reinterpret_cast<const float4*>(inp)[(size_t)b * T_LEN];
    const float p = x0.x, pet = x0.y, rsmax = x0.z, area = x0.w;

    const float INT = fminf(fminf(pr.insc, pet), p);
    const float INR = p - INT;

    // RS after step 0, exact from zero state: sms=0 -> ratio=0, infil=C; gw=0 -> BAS0=0
    const float RMO0   = fminf(pr.C, INR);
    const float IRUN0  = INR - RMO0;
    const float infl0  = IRUN0 * area;
    const float xr0    = infl0 - rsmax;
    const float Qor0   = fmaxf(xr0, 0.f);
    const float Qir0   = (xr0 > 0.f) ? (pr.kr * rsmax) : 0.f;   // rs=0 -> power term = 0
    const float rs0    = infl0 - Qor0 - Qir0;

    // post-pass with SMS1 = final sms, GW1 = final gw
    const float smsF  = ws[b * 2 + 0];
    const float gwF   = ws[b * 2 + 1];
    const float smsc  = fminf(fmaxf(smsF, 0.f), pr.S);
    const float ratio = smsc * pr.invS;
    const float infil = pr.C * __expf(pr.eca * smsc);
    const float RMO   = fminf(infil, INR);
    const float IRUN  = INR - RMO;
    const float SRUN  = pr.sub * ratio * RMO;
    const float BAS   = pr.rk * fmaxf(gwF, 0.f);

    const float inflow = (IRUN + SRUN + BAS) * area;
    const float rinv   = __builtin_amdgcn_rcpf(rsmax);
    const float xq     = (rs0 + inflow) - rsmax;
    const float Qor2   = fmaxf(xq, 0.f);
    const float r2     = rs0 * rinv;
    const float Qir2   = (xq > 0.f) ? (pr.kr * rsmax)
                                    : (pr.kr * rs0 * (r2 * __builtin_amdgcn_sqrtf(r2)));
    const float oma    = 1.f - area;
    const float dra    = (SRUN + IRUN) * oma + Qir2 + Qor2 - pr.ls;
    out[(size_t)b * T_LEN] = fmaxf(fmaxf(dra, 0.f) + BAS * oma, 0.f);
}

extern "C" void kernel_launch(void* const* d_in, const int* in_sizes, int n_in,
                              void* d_out, int out_size, void* d_ws, size_t ws_size,
                              hipStream_t stream) {
    const float* inp = (const float*)d_in[0];
    float* out = (float*)d_out;
    float* ws  = (float*)d_ws;   // 4096 * 2 floats

    const int blocks = NCHUNK * (NCH / WPC);    // 64 x 64 = 4096 blocks, 1 wave each
    hirnn_chunk_kernel<<<blocks, WPC, 0, stream>>>(
        inp,
        (const float*)d_in[1], (const float*)d_in[2], (const float*)d_in[3],
        (const float*)d_in[4], (const float*)d_in[5], (const float*)d_in[6],
        (const float*)d_in[7], (const float*)d_in[8], (const float*)d_in[9],
        (const float*)d_in[10],
        out, ws);

    hirnn_t0_kernel<<<NCH / 256, 256, 0, stream>>>(
        inp,
        (const float*)d_in[1], (const float*)d_in[2], (const float*)d_in[3],
        (const float*)d_in[4], (const float*)d_in[5], (const float*)d_in[6],
        (const float*)d_in[7], (const float*)d_in[8], (const float*)d_in[9],
        (const float*)d_in[10],
        ws, out);
}

// Round 8
// 319.282 us; speedup vs baseline: 1.3592x; 1.3592x over previous
//
#include <hip/hip_runtime.h>

#define T_LEN  2048
#define NCH    4096     // chains (B)
#define CH     64       // chunk length (timesteps per output chunk)
#define NCHUNK (T_LEN / CH)
#define WARM   256      // warm-up steps before each chunk (chunks 0-3: truncated, exact)
#define TK     8        // timesteps per LDS tile
#define NBUF   2        // double buffer: 2 x 16 KB = 32 KB -> 4 blocks/CU
#define GPW    2        // chain-groups (of 64) per wave: ILP=2 per lane

__device__ __forceinline__ float clampf(float x, float lo, float hi) {
    return fminf(fmaxf(x, lo), hi);
}

struct Params {
    float insc, C, S, sub, crak, rk, kr, lg, ls, invS, eca;
};

__device__ __forceinline__ Params mkparams(
    const float* pINSC, const float* pCOEFF, const float* pSQ, const float* pSMSC,
    const float* pSUB, const float* pCRAK, const float* pRecK, const float* pKr,
    const float* pLG, const float* pLS)
{
    Params pr;
    pr.insc = clampf(pINSC[0] * 5.f,   0.5f,   5.f);
    pr.C    = clampf(pCOEFF[0] * 400.f, 50.f,  400.f);
    float q = clampf(pSQ[0] * 6.f,     0.f,    6.f);
    pr.S    = clampf(pSMSC[0] * 500.f, 50.f,   500.f);
    pr.sub  = clampf(pSUB[0],          0.f,    1.f);
    pr.crak = clampf(pCRAK[0],         0.f,    1.f);
    pr.rk   = clampf(pRecK[0] * 0.3f,  0.003f, 0.3f);
    pr.kr   = clampf(pKr[0] * 0.1f,    0.01f,  0.1f);
    pr.lg   = clampf(pLG[0] * 0.1f,    0.001f, 0.1f);
    pr.ls   = clampf(pLS[0] * 10.f,    0.01f,  10.f);
    pr.invS = 1.0f / pr.S;
    pr.eca  = -q * pr.invS;
    return pr;
}

// HBM -> LDS direct. LDS dest is wave-uniform base + lane*16; global src per-lane.
__device__ __forceinline__ void gload_lds16(const float4* g, float4* l) {
    __builtin_amdgcn_global_load_lds(
        (const __attribute__((address_space(1))) void*)(g),
        (__attribute__((address_space(3))) void*)(l),
        16, 0, 0);
}

// One recurrence step. OUT=true additionally computes the fused post-pass Q.
template <bool OUT>
__device__ __forceinline__ float step_one(const Params& pr, const float4& xv,
                                          float& sms, float& gw, float& rs)
{
    const float p = xv.x, pet = xv.y, rsmax = xv.z, area = xv.w;

    const float INT  = fminf(fminf(pr.insc, pet), p);
    const float INR  = p - INT;
    const float smsc  = fminf(fmaxf(sms, 0.f), pr.S);
    const float ratio = smsc * pr.invS;
    const float infil = pr.C * __expf(pr.eca * smsc);
    const float RMO   = fminf(infil, INR);
    const float IRUN  = INR - RMO;
    const float SRUN  = pr.sub * ratio * RMO;
    const float REC   = pr.crak * ratio * (RMO - SRUN);
    const float SMF   = (RMO - SRUN) - REC;
    const float POT   = pet - INT;              // INT <= pet always
    const float ETS   = fminf(POT, 10.f * ratio);
    const float nsms  = smsc + (SMF - ETS);
    const float RECn  = REC + fmaxf(nsms - pr.S, 0.f);
    const float BAS   = pr.rk * fmaxf(gw, 0.f);
    const float ngw   = (gw - pr.lg) + (RECn - BAS);
    const float inflow = (IRUN + SRUN + BAS) * area;
    const float rinv   = __builtin_amdgcn_rcpf(rsmax);
    const float xr     = (rs + inflow) - rsmax;
    const float Qor    = fmaxf(xr, 0.f);
    const float rrt    = rs * rinv;
    const float Qir    = (xr > 0.f) ? (pr.kr * rsmax)
                                    : (pr.kr * rs * (rrt * __builtin_amdgcn_sqrtf(rrt)));
    const float nrs    = rs + ((inflow - Qor) - Qir);

    float q = 0.f;
    if constexpr (OUT) {
        const float xq   = (nrs + inflow) - rsmax;
        const float Qor2 = fmaxf(xq, 0.f);
        const float r2   = nrs * rinv;
        const float Qir2 = (xq > 0.f) ? (pr.kr * rsmax)
                                      : (pr.kr * nrs * (r2 * __builtin_amdgcn_sqrtf(r2)));
        const float oma  = 1.f - area;
        const float dra  = (SRUN + IRUN) * oma + Qir2 + Qor2 - pr.ls;
        q = fmaxf(fmaxf(dra, 0.f) + BAS * oma, 0.f);
    }

    sms = nsms; gw = ngw; rs = nrs;
    return q;
}

// ---------------- main chunked scan kernel (ILP=2 per lane) ----------------
// 1 wave per block; wave covers TWO 64-chain groups (lane l -> chains cbase+l
// and cbase+64+l). 32 chunks x 32 wave-groups = 1024 blocks = 4/CU (fully
// resident), 1 wave/SIMD. Rationale: the ~550 cyc/step per-wave stall
// (R1/R3/R6 fit) is an in-order dependency stall that TLP does NOT hide
// (R3: 43% issue eff at W=2). Two independent chains per lane let the
// compile-time scheduler fill one chain's bubbles with the other's issue.
//
// Per 8-step tile: [128 chains x 8 steps] staged HBM->LDS via 16
// global_load_lds (8 contiguous 128B segments each), double-buffered.
// vmcnt discipline (in-order retirement): issue next-tile loads BEFORE this
// tile's stores; at loop top wait vmcnt(4) if prev tile stored (4 newer
// stores outstanding) else vmcnt(0) -> never waits on stores.
//
// Block decode: blk = chunk*32 + wg; overlapping warm windows spaced 32 apart
// = same XCD (32 % 8 == 0) -> L2 absorbs warm re-reads (R4 lesson).
// Step index XOR-swizzled on the GLOBAL source (LDS linear): slot (row, c)
// holds step c ^ (row&7).
__global__ __launch_bounds__(64, 4)
void hirnn_chunk_kernel(const float* __restrict__ inp,
                        const float* __restrict__ pINSC, const float* __restrict__ pCOEFF,
                        const float* __restrict__ pSQ,   const float* __restrict__ pSMSC,
                        const float* __restrict__ pSUB,  const float* __restrict__ pCRAK,
                        const float* __restrict__ pRecK, const float* __restrict__ pKr,
                        const float* __restrict__ pLG,   const float* __restrict__ pLS,
                        float* __restrict__ out, float* __restrict__ ws)
{
    __shared__ float4 buf[NBUF][64 * GPW * TK];   // 2 x 16 KB

    const int l     = threadIdx.x;                // lane 0..63
    const int blk   = blockIdx.x;
    const int chunk = blk >> 5;                   // 32 wave-groups per chunk
    const int wg    = blk & 31;
    const int cbase = wg * 128;                   // 128 chains per wave

    const Params pr = mkparams(pINSC, pCOEFF, pSQ, pSMSC, pSUB, pCRAK, pRecK, pKr, pLG, pLS);

    // Staging: instr k (0..15) covers rows 8k..8k+7 (row = 8k + (l>>3)),
    // col = l&7, global step = t0 + ((l&7) ^ (l>>3)) -> 8 x 128B segments.
    const float4* __restrict__ gl =
        reinterpret_cast<const float4*>(inp)
        + (size_t)(cbase + (l >> 3)) * T_LEN + ((l & 7) ^ (l >> 3));

    float4* __restrict__ qoutA = reinterpret_cast<float4*>(out + (size_t)(cbase + l) * T_LEN);
    float4* __restrict__ qoutB = reinterpret_cast<float4*>(out + (size_t)(cbase + 64 + l) * T_LEN);

    const int t_start = chunk * CH;
    const int t_warm  = (t_start >= WARM) ? (t_start - WARM) : 0;
    const int t_end   = t_start + CH;

    float smsA = 0.f, gwA = 0.f, rsA = 0.f;
    float smsB = 0.f, gwB = 0.f, rsB = 0.f;

    auto issue_tile = [&](float4* dst, int t0) {
#pragma unroll
        for (int k = 0; k < 2 * TK; ++k)          // 16 loads
            gload_lds16(gl + (size_t)(k * 8) * T_LEN + t0, dst + k * 64);
    };

    issue_tile(&buf[0][0], t_warm);               // prologue

    const int ra = l * TK;                        // stream A row base (row = l)
    const int rb = (64 + l) * TK;                 // stream B row base (row = 64+l)
    const int rx = l & 7;                         // read-side XOR (same for A and B)

    int p = 0;
    for (int t0 = t_warm; t0 < t_end; t0 += TK, p ^= 1) {
        // wait for THIS tile's 16 loads (oldest); prev tile's 4 stores are newer
        if (t0 > t_start) asm volatile("s_waitcnt vmcnt(4)" ::: "memory");
        else              asm volatile("s_waitcnt vmcnt(0)" ::: "memory");
        __builtin_amdgcn_sched_barrier(0);

        const float4* bp = &buf[p][0];

        if (t0 < t_start) {                       // ---- warm-up: state only ----
#pragma unroll
            for (int h = 0; h < 2; ++h) {
                float4 xa[4], xb[4];
#pragma unroll
                for (int s = 0; s < 4; ++s) {
                    const int sc = h * 4 + s;
                    xa[s] = bp[ra + (sc ^ rx)];
                    xb[s] = bp[rb + (sc ^ rx)];
                }
#pragma unroll
                for (int s = 0; s < 4; ++s) {
                    step_one<false>(pr, xa[s], smsA, gwA, rsA);
                    step_one<false>(pr, xb[s], smsB, gwB, rsB);
                }
            }
            if (t0 + TK < t_end) issue_tile(&buf[p ^ 1][0], t0 + TK);
        } else {                                  // ---- output phase ----
            float qa[TK], qb[TK];
#pragma unroll
            for (int h = 0; h < 2; ++h) {
                float4 xa[4], xb[4];
#pragma unroll
                for (int s = 0; s < 4; ++s) {
                    const int sc = h * 4 + s;
                    xa[s] = bp[ra + (sc ^ rx)];
                    xb[s] = bp[rb + (sc ^ rx)];
                }
#pragma unroll
                for (int s = 0; s < 4; ++s) {
                    qa[h * 4 + s] = step_one<true>(pr, xa[s], smsA, gwA, rsA);
                    qb[h * 4 + s] = step_one<true>(pr, xb[s], smsB, gwB, rsB);
                }
            }
            // issue next-tile loads BEFORE stores (stores stay newest in vmcnt order)
            if (t0 + TK < t_end) issue_tile(&buf[p ^ 1][0], t0 + TK);
            float4 wv;
#pragma unroll
            for (int h = 0; h < 2; ++h) {
                wv.x = qa[4*h+0]; wv.y = qa[4*h+1]; wv.z = qa[4*h+2]; wv.w = qa[4*h+3];
                qoutA[t0 / 4 + h] = wv;
                wv.x = qb[4*h+0]; wv.y = qb[4*h+1]; wv.z = qb[4*h+2]; wv.w = qb[4*h+3];
                qoutB[t0 / 4 + h] = wv;
            }
        }
    }

    if (chunk == NCHUNK - 1) {                    // final state for the t==0 fix-up
        ws[(cbase + l) * 2 + 0]      = smsA;
        ws[(cbase + l) * 2 + 1]      = gwA;
        ws[(cbase + 64 + l) * 2 + 0] = smsB;
        ws[(cbase + 64 + l) * 2 + 1] = gwB;
    }
}

// ---------------- t == 0 fix-up kernel ----------------
__global__ __launch_bounds__(256)
void hirnn_t0_kernel(const float* __restrict__ inp,
                     const float* __restrict__ pINSC, const float* __restrict__ pCOEFF,
                     const float* __restrict__ pSQ,   const float* __restrict__ pSMSC,
                     const float* __restrict__ pSUB,  const float* __restrict__ pCRAK,
                     const float* __restrict__ pRecK, const float* __restrict__ pKr,
                     const float* __restrict__ pLG,   const float* __restrict__ pLS,
                     const float* __restrict__ ws, float* __restrict__ out)
{
    const int b = blockIdx.x * blockDim.x + threadIdx.x;
    if (b >= NCH) return;

    const Params pr = mkparams(pINSC, pCOEFF, pSQ, pSMSC, pSUB, pCRAK, pRecK, pKr, pLG, pLS);

    const float4 x0 = reinterpret_cast<const float4*>(inp)[(size_t)b * T_LEN];
    const float p = x0.x, pet = x0.y, rsmax = x0.z, area = x0.w;

    const float INT = fminf(fminf(pr.insc, pet), p);
    const float INR = p - INT;

    const float RMO0   = fminf(pr.C, INR);
    const float IRUN0  = INR - RMO0;
    const float infl0  = IRUN0 * area;
    const float xr0    = infl0 - rsmax;
    const float Qor0   = fmaxf(xr0, 0.f);
    const float Qir0   = (xr0 > 0.f) ? (pr.kr * rsmax) : 0.f;
    const float rs0    = infl0 - Qor0 - Qir0;

    const float smsF  = ws[b * 2 + 0];
    const float gwF   = ws[b * 2 + 1];
    const float smsc  = fminf(fmaxf(smsF, 0.f), pr.S);
    const float ratio = smsc * pr.invS;
    const float infil = pr.C * __expf(pr.eca * smsc);
    const float RMO   = fminf(infil, INR);
    const float IRUN  = INR - RMO;
    const float SRUN  = pr.sub * ratio * RMO;
    const float BAS   = pr.rk * fmaxf(gwF, 0.f);

    const float inflow = (IRUN + SRUN + BAS) * area;
    const float rinv   = __builtin_amdgcn_rcpf(rsmax);
    const float xq     = (rs0 + inflow) - rsmax;
    const float Qor2   = fmaxf(xq, 0.f);
    const float r2     = rs0 * rinv;
    const float Qir2   = (xq > 0.f) ? (pr.kr * rsmax)
                                    : (pr.kr * rs0 * (r2 * __builtin_amdgcn_sqrtf(r2)));
    const float oma    = 1.f - area;
    const float dra    = (SRUN + IRUN) * oma + Qir2 + Qor2 - pr.ls;
    out[(size_t)b * T_LEN] = fmaxf(fmaxf(dra, 0.f) + BAS * oma, 0.f);
}

extern "C" void kernel_launch(void* const* d_in, const int* in_sizes, int n_in,
                              void* d_out, int out_size, void* d_ws, size_t ws_size,
                              hipStream_t stream) {
    const float* inp = (const float*)d_in[0];
    float* out = (float*)d_out;
    float* ws  = (float*)d_ws;   // 4096 * 2 floats

    const int blocks = NCHUNK * (NCH / (64 * GPW));   // 32 x 32 = 1024 blocks, 1 wave each
    hirnn_chunk_kernel<<<blocks, 64, 0, stream>>>(
        inp,
        (const float*)d_in[1], (const float*)d_in[2], (const float*)d_in[3],
        (const float*)d_in[4], (const float*)d_in[5], (const float*)d_in[6],
        (const float*)d_in[7], (const float*)d_in[8], (const float*)d_in[9],
        (const float*)d_in[10],
        out, ws);

    hirnn_t0_kernel<<<NCH / 256, 256, 0, stream>>>(
        inp,
        (const float*)d_in[1], (const float*)d_in[2], (const float*)d_in[3],
        (const float*)d_in[4], (const float*)d_in[5], (const float*)d_in[6],
        (const float*)d_in[7], (const float*)d_in[8], (const float*)d_in[9],
        (const float*)d_in[10],
        ws, out);
}